// Round 1
// baseline (505.705 us; speedup 1.0000x reference)
//
#include <hip/hip_runtime.h>

// Sorted-segment product:
//   out[i] = prod_{j : csr[j]==i} x[ptrs[j]]   (empty segment -> 0)
//
// csr is sorted, so each segment is a contiguous run. Each thread takes a
// contiguous chunk of K edges. A run is OWNED by the thread whose chunk
// contains its global start (csr[pos-1] != csr[pos]). The owner multiplies
// through the run, walking forward across chunk boundaries if needed
// (runs are short: Poisson(4)). The owner of each run start also writes 0
// to the gap of empty segment ids before it. => every out element written
// exactly once, no atomics, no pre-zero pass.

#define K 8  // edges per thread; E=16.7M -> 2.1M threads

__global__ __launch_bounds__(256) void prodseg_kernel(
    const float* __restrict__ x,
    const int*   __restrict__ ptrs,
    const int*   __restrict__ csr,
    float*       __restrict__ out,
    int E, int S)
{
    int t = blockIdx.x * blockDim.x + threadIdx.x;
    int base = t * K;
    if (base >= E) return;

    // segment id just before our chunk (-1 sentinel at array start)
    int prev = (base == 0) ? -1 : csr[base - 1];

    int   seg[K];
    int   pt[K];
    float g[K];
    int n;

    if (base + K <= E) {
        n = K;
        // base is a multiple of 8 -> 32B aligned, int4 loads are safe
        const int4* c4 = reinterpret_cast<const int4*>(csr + base);
        int4 c0 = c4[0], c1 = c4[1];
        seg[0]=c0.x; seg[1]=c0.y; seg[2]=c0.z; seg[3]=c0.w;
        seg[4]=c1.x; seg[5]=c1.y; seg[6]=c1.z; seg[7]=c1.w;
        const int4* p4 = reinterpret_cast<const int4*>(ptrs + base);
        int4 p0 = p4[0], p1 = p4[1];
        pt[0]=p0.x; pt[1]=p0.y; pt[2]=p0.z; pt[3]=p0.w;
        pt[4]=p1.x; pt[5]=p1.y; pt[6]=p1.z; pt[7]=p1.w;
    } else {
        n = E - base;
        for (int k = 0; k < K; ++k) {
            int idx = base + (k < n ? k : 0);
            seg[k] = csr[idx];
            pt[k]  = ptrs[idx];
        }
    }

    // issue all gathers up front so their latencies overlap
    #pragma unroll
    for (int k = 0; k < K; ++k) g[k] = x[pt[k]];

    int   cur = seg[0];
    bool  own = (cur != prev);
    float prod = own ? g[0] : 1.0f;
    if (own) {
        // zero the empty-segment gap before our first owned run
        for (int q = prev + 1; q < cur; ++q) out[q] = 0.0f;
    }

    #pragma unroll
    for (int k = 1; k < K; ++k) {
        if (k >= n) break;
        int s = seg[k];
        if (s == cur) {
            prod *= g[k];             // harmless if !own (never stored)
        } else {
            if (own) out[cur] = prod; // run ended inside chunk
            // zero empty segments between cur and s (new run start is ours)
            for (int q = cur + 1; q < s; ++q) out[q] = 0.0f;
            cur  = s;
            own  = true;
            prod = g[k];
        }
    }

    // final run of the chunk: if owned, walk forward across chunk boundary
    if (own) {
        int idx = base + n;
        while (idx < E && csr[idx] == cur) {
            prod *= x[ptrs[idx]];
            ++idx;
        }
        out[cur] = prod;
        // safety: if we owned the very last segment of the array, zero any
        // trailing out elements (setup pins csr[E-1]=S-1, so this is empty)
        if (idx == E) {
            for (int q = cur + 1; q < S; ++q) out[q] = 0.0f;
        }
    }
}

extern "C" void kernel_launch(void* const* d_in, const int* in_sizes, int n_in,
                              void* d_out, int out_size, void* d_ws, size_t ws_size,
                              hipStream_t stream) {
    const float* x    = (const float*)d_in[0];
    const int*   ptrs = (const int*)d_in[1];
    const int*   csr  = (const int*)d_in[2];
    float*       out  = (float*)d_out;
    int E = in_sizes[1];
    int S = out_size;

    int nthreads = (E + K - 1) / K;
    dim3 block(256);
    dim3 grid((nthreads + block.x - 1) / block.x);
    prodseg_kernel<<<grid, block, 0, stream>>>(x, ptrs, csr, out, E, S);
}